// Round 1
// baseline (159.597 us; speedup 1.0000x reference)
//
#include <hip/hip_runtime.h>

#define BB 8
#define S_ENC 256
#define S_DEC 128
#define DM 512
#define UN 512

// ---------------------------------------------------------------------------
// Kernel 1: projections.
//   d_encT[b, u, e] = sum_d enc[b,e,d] * W_enc[d,u] + bias_enc[u]   (transposed store)
//   d_dec [b, q, u] = sum_d dec[b,q,d] * W_dec[d,u] + bias_dec[u]
// 64x64 output tile per block, 256 threads, 4x4 acc per thread, K staged 16-wide.
// ---------------------------------------------------------------------------
__global__ __launch_bounds__(256) void proj_kernel(
    const float* __restrict__ enc,       // [B*S_ENC, 512]
    const float* __restrict__ dec,       // [B*S_DEC, 512]
    const float* __restrict__ Wenc,      // [512,512]
    const float* __restrict__ Wdec,      // [512,512]
    const float* __restrict__ bias_enc,  // [512]
    const float* __restrict__ bias_dec,  // [512]
    float* __restrict__ d_encT,          // [B, 512, 256]
    float* __restrict__ d_dec)           // [B*S_DEC, 512]
{
    __shared__ float As[16][68];   // [k][row], pad 68 keeps 16B alignment, <=2-way banks
    __shared__ float Bs[16][68];   // [k][col]

    const int bid = blockIdx.x;
    const int ct  = bid & 7;       // col tile (8 tiles of 64 over 512)
    const int mt  = bid >> 3;      // row tile 0..47 (0..31 enc, 32..47 dec)
    const bool is_enc = (mt < 32);

    const float* A    = is_enc ? enc      : dec;
    const float* W    = is_enc ? Wenc     : Wdec;
    const float* bias = is_enc ? bias_enc : bias_dec;
    const int row0 = is_enc ? (mt * 64) : ((mt - 32) * 64);
    const int c0   = ct * 64;

    const int tid = threadIdx.x;
    const int tx = tid & 15;       // col group (4 cols each)
    const int ty = tid >> 4;       // row group (4 rows each)

    float acc[4][4];
#pragma unroll
    for (int i = 0; i < 4; ++i)
#pragma unroll
        for (int j = 0; j < 4; ++j) acc[i][j] = 0.f;

    const int r_st  = tid >> 2;          // staging row 0..63
    const int k4_st = (tid & 3) << 2;    // staging k sub 0,4,8,12
    const int kb_st = tid >> 4;          // B-stage k 0..15
    const int c4_st = (tid & 15) << 2;   // B-stage col sub

    for (int k0 = 0; k0 < 512; k0 += 16) {
        float4 ga = *(const float4*)&A[(row0 + r_st) * 512 + k0 + k4_st];
        float4 gb = *(const float4*)&W[(k0 + kb_st) * 512 + c0 + c4_st];
        As[k4_st + 0][r_st] = ga.x;
        As[k4_st + 1][r_st] = ga.y;
        As[k4_st + 2][r_st] = ga.z;
        As[k4_st + 3][r_st] = ga.w;
        *(float4*)&Bs[kb_st][c4_st] = gb;
        __syncthreads();
#pragma unroll
        for (int kk = 0; kk < 16; ++kk) {
            float4 av = *(float4*)&As[kk][ty << 2];
            float4 bv = *(float4*)&Bs[kk][tx << 2];
            float ar[4] = {av.x, av.y, av.z, av.w};
            float br[4] = {bv.x, bv.y, bv.z, bv.w};
#pragma unroll
            for (int i = 0; i < 4; ++i)
#pragma unroll
                for (int j = 0; j < 4; ++j)
                    acc[i][j] = fmaf(ar[i], br[j], acc[i][j]);
        }
        __syncthreads();
    }

    float4 b4 = *(const float4*)&bias[c0 + (tx << 2)];
    float br[4] = {b4.x, b4.y, b4.z, b4.w};

    if (is_enc) {
        // transposed scattered store: d_encT[(b*512 + u)*256 + e]
#pragma unroll
        for (int i = 0; i < 4; ++i) {
            int r = row0 + (ty << 2) + i;      // flattened (b,e)
            int bb = r >> 8, e = r & 255;
#pragma unroll
            for (int j = 0; j < 4; ++j) {
                int u = c0 + (tx << 2) + j;
                d_encT[((bb << 9) + u) * 256 + e] = acc[i][j] + br[j];
            }
        }
    } else {
#pragma unroll
        for (int i = 0; i < 4; ++i) {
            int r = row0 + (ty << 2) + i;      // flattened (b,q)
            float4 o = make_float4(acc[i][0] + br[0], acc[i][1] + br[1],
                                   acc[i][2] + br[2], acc[i][3] + br[3]);
            *(float4*)&d_dec[r * 512 + c0 + (tx << 2)] = o;
        }
    }
}

// ---------------------------------------------------------------------------
// Kernel 2: fused scores + softmax + context.
// Grid: 256 blocks = (b in 8) x (q-tile of 4 in 32). 512 threads = 8 waves.
// Waves: 4 e-strips (64 e each) x 2 u-halves (256 u each).
// score identity: sum_u w_u tanh(x) = sum(w) - 2*sum_u w_u / (1+e^{2x});
// sum(w) and bias_score are constant shifts -> cancelled by softmax.
// ---------------------------------------------------------------------------
__global__ __launch_bounds__(512) void attend_kernel(
    const float* __restrict__ enc,     // [B, 256, 512]
    const float* __restrict__ d_encT,  // [B, 512, 256]
    const float* __restrict__ d_dec,   // [B, 128, 512]
    const float* __restrict__ Wscore,  // [512]
    float* __restrict__ out)           // [B, 128, 512]
{
    __shared__ float ddc[UN * 4];        // [u][q], pre-scaled by 2*log2(e)
    __shared__ float wsc[UN];
    __shared__ float accs[2][4][256];    // [u-half][q][e]
    __shared__ float wT[256][4];         // softmax weights [e][q]

    const float C = 2.8853900817779268f;       // 2*log2(e)
    const float LOG2E = 1.4426950408889634f;

    const int bid = blockIdx.x;
    const int b = bid >> 5, qt = bid & 31, q0 = qt << 2;
    const int tid = threadIdx.x;

    // stage dd * C into [u][q] layout
    {
        int q = tid >> 7, u4 = (tid & 127) << 2;
        float4 v = *(const float4*)&d_dec[((b * S_DEC) + q0 + q) * UN + u4];
        ddc[(u4 + 0) * 4 + q] = v.x * C;
        ddc[(u4 + 1) * 4 + q] = v.y * C;
        ddc[(u4 + 2) * 4 + q] = v.z * C;
        ddc[(u4 + 3) * 4 + q] = v.w * C;
    }
    if (tid < 128) {
        *(float4*)&wsc[tid << 2] = *(const float4*)&Wscore[tid << 2];
    }
    __syncthreads();

    const int wv = tid >> 6, lane = tid & 63;
    const int e = ((wv & 3) << 6) + lane;
    const int uh = wv >> 2, u0 = uh << 8;

    float a0 = 0.f, a1 = 0.f, a2 = 0.f, a3 = 0.f;
    const float* dptr = d_encT + ((size_t)b << 17) + e;   // + u*256 per step
#pragma unroll 4
    for (int u = u0; u < u0 + 256; ++u) {
        float de = dptr[u << 8];
        float4 dq = *(float4*)&ddc[u << 2];   // wave-uniform broadcast
        float w  = wsc[u];
        float t  = de * C;
        float s0 = t + dq.x, s1 = t + dq.y, s2 = t + dq.z, s3 = t + dq.w;
        float r0 = __builtin_amdgcn_rcpf(1.0f + __builtin_amdgcn_exp2f(s0));
        float r1 = __builtin_amdgcn_rcpf(1.0f + __builtin_amdgcn_exp2f(s1));
        float r2 = __builtin_amdgcn_rcpf(1.0f + __builtin_amdgcn_exp2f(s2));
        float r3 = __builtin_amdgcn_rcpf(1.0f + __builtin_amdgcn_exp2f(s3));
        a0 = fmaf(w, r0, a0);
        a1 = fmaf(w, r1, a1);
        a2 = fmaf(w, r2, a2);
        a3 = fmaf(w, r3, a3);
    }
    accs[uh][0][e] = a0;
    accs[uh][1][e] = a1;
    accs[uh][2][e] = a2;
    accs[uh][3][e] = a3;
    __syncthreads();

    // softmax over e (256) per q; logits = -2 * (acc_half0 + acc_half1)
    if (wv < 4) {
        const int q = wv;
        float l[4];
        float m = -1e30f;
#pragma unroll
        for (int i = 0; i < 4; ++i) {
            int ee = lane + (i << 6);
            float a = accs[0][q][ee] + accs[1][q][ee];
            l[i] = -2.f * a;
            m = fmaxf(m, l[i]);
        }
#pragma unroll
        for (int mk = 32; mk >= 1; mk >>= 1) m = fmaxf(m, __shfl_xor(m, mk, 64));
        float p[4];
        float s = 0.f;
#pragma unroll
        for (int i = 0; i < 4; ++i) {
            p[i] = __builtin_amdgcn_exp2f((l[i] - m) * LOG2E);
            s += p[i];
        }
#pragma unroll
        for (int mk = 32; mk >= 1; mk >>= 1) s += __shfl_xor(s, mk, 64);
        float inv = __builtin_amdgcn_rcpf(s);
#pragma unroll
        for (int i = 0; i < 4; ++i) wT[lane + (i << 6)][q] = p[i] * inv;
    }
    __syncthreads();

    // context: out[b, q0+q, d] = sum_e wT[e][q] * enc[b,e,d]
    const int d = tid;  // 0..511
    float c0_ = 0.f, c1_ = 0.f, c2_ = 0.f, c3_ = 0.f;
    const float* ep = enc + ((size_t)b * S_ENC) * DM + d;
#pragma unroll 4
    for (int ee = 0; ee < 256; ++ee) {
        float4 w4 = *(float4*)&wT[ee][0];   // wave-uniform broadcast
        float x = ep[ee << 9];
        c0_ = fmaf(w4.x, x, c0_);
        c1_ = fmaf(w4.y, x, c1_);
        c2_ = fmaf(w4.z, x, c2_);
        c3_ = fmaf(w4.w, x, c3_);
    }
    float* op = out + ((size_t)(b * S_DEC) + q0) * DM + d;
    op[0]    = c0_;
    op[512]  = c1_;
    op[1024] = c2_;
    op[1536] = c3_;
}

// ---------------------------------------------------------------------------
extern "C" void kernel_launch(void* const* d_in, const int* in_sizes, int n_in,
                              void* d_out, int out_size, void* d_ws, size_t ws_size,
                              hipStream_t stream) {
    const float* enc      = (const float*)d_in[0];  // [8,256,512]
    const float* dec      = (const float*)d_in[1];  // [8,128,512]
    const float* Wenc     = (const float*)d_in[2];  // [512,512]
    const float* Wdec     = (const float*)d_in[3];  // [512,512]
    const float* Wscore   = (const float*)d_in[4];  // [512,1]
    const float* bias_enc = (const float*)d_in[5];  // [512]
    const float* bias_dec = (const float*)d_in[6];  // [512]
    // d_in[7] = bias_score: constant shift, cancelled by softmax.
    float* out = (float*)d_out;

    float* ws = (float*)d_ws;
    float* d_encT = ws;                        // 8*512*256 floats = 4 MB
    float* d_decP = ws + (size_t)BB * 512 * 256; // 8*128*512 floats = 2 MB

    proj_kernel<<<384, 256, 0, stream>>>(enc, dec, Wenc, Wdec, bias_enc, bias_dec,
                                         d_encT, d_decP);
    attend_kernel<<<256, 512, 0, stream>>>(enc, d_encT, d_decP, Wscore, out);
}

// Round 2
// 157.684 us; speedup vs baseline: 1.0121x; 1.0121x over previous
//
#include <hip/hip_runtime.h>

#define BB 8
#define S_ENC 256
#define S_DEC 128
#define DM 512
#define UN 512

// ---------------------------------------------------------------------------
// Kernel 1: projections. Unified 64x64-tile fp32 GEMM, 256 thr, 4x4 acc,
// BK=16, register-prefetch double buffering.
//   enc blocks (bid<256): rows = u (A = W_enc staged column-wise), cols = e
//       -> d_encT[b,u,e] stored coalesced. u0=(bid>>5)*64, (b,e0)=(bid&31)*64.
//   dec blocks (bid>=256): rows = (b,q) flat, cols = u -> d_dec row-major.
// ---------------------------------------------------------------------------
__global__ __launch_bounds__(256) void proj_kernel(
    const float* __restrict__ enc,       // [B*S_ENC, 512]
    const float* __restrict__ dec,       // [B*S_DEC, 512]
    const float* __restrict__ Wenc,      // [512,512]
    const float* __restrict__ Wdec,      // [512,512]
    const float* __restrict__ bias_enc,  // [512]
    const float* __restrict__ bias_dec,  // [512]
    float* __restrict__ d_encT,          // [B, 512, 256]
    float* __restrict__ d_dec)           // [B*S_DEC, 512]
{
    __shared__ float SB[2][16][68];   // SB[0]=As(rows), SB[1]=Bs(cols)

    const int bid = blockIdx.x;
    const bool is_enc = (bid < 256);
    const int tid = threadIdx.x;
    const int tx = tid & 15;          // col group (4 cols each)
    const int ty = tid >> 4;          // row group (4 rows each)

    // scat: [64 rows x 512 k] row-major source, scalar-scattered into SB[sd][k][row]
    // dir : [512 k x 512 cols] source, float4 rows into SB[1-sd][k][col]
    const float* scat_src; int scat_row0;
    const float* dir_src;  int dir_col0;
    int sd;
    if (is_enc) {
        scat_src = enc;  scat_row0 = (bid & 31) << 6;   // flattened (b,e)
        dir_src  = Wenc; dir_col0  = (bid >> 5) << 6;   // u0 (tile ROWS)
        sd = 1;                                          // enc data -> Bs (cols=e)
    } else {
        int b2 = bid - 256;
        scat_src = dec;  scat_row0 = (b2 >> 3) << 6;    // flattened (b,q)
        dir_src  = Wdec; dir_col0  = (b2 & 7) << 6;     // c0 (tile COLS)
        sd = 0;                                          // dec data -> As (rows)
    }
    const int dd = 1 - sd;

    const int s_row = tid >> 2;          // 0..63
    const int s_k4  = (tid & 3) << 2;    // 0,4,8,12
    const int d_k   = tid >> 4;          // 0..15
    const int d_c4  = (tid & 15) << 2;   // 0..60

    const float* sp = &scat_src[(scat_row0 + s_row) * 512 + s_k4];
    const float* dp = &dir_src[d_k * 512 + dir_col0 + d_c4];

    float4 gs = *(const float4*)sp;       // prologue prefetch (k0 = 0)
    float4 gd = *(const float4*)dp;

    float acc[4][4];
#pragma unroll
    for (int i = 0; i < 4; ++i)
#pragma unroll
        for (int j = 0; j < 4; ++j) acc[i][j] = 0.f;

    for (int k0 = 0; k0 < 512; k0 += 16) {
        SB[sd][s_k4 + 0][s_row] = gs.x;
        SB[sd][s_k4 + 1][s_row] = gs.y;
        SB[sd][s_k4 + 2][s_row] = gs.z;
        SB[sd][s_k4 + 3][s_row] = gs.w;
        *(float4*)&SB[dd][d_k][d_c4] = gd;
        __syncthreads();
        if (k0 + 16 < 512) {              // prefetch next tile; overlaps compute
            gs = *(const float4*)(sp + k0 + 16);
            gd = *(const float4*)(dp + (size_t)(k0 + 16) * 512);
        }
#pragma unroll
        for (int kk = 0; kk < 16; ++kk) {
            float4 av = *(float4*)&SB[0][kk][ty << 2];
            float4 bv = *(float4*)&SB[1][kk][tx << 2];
            float ar[4] = {av.x, av.y, av.z, av.w};
            float br[4] = {bv.x, bv.y, bv.z, bv.w};
#pragma unroll
            for (int i = 0; i < 4; ++i)
#pragma unroll
                for (int j = 0; j < 4; ++j)
                    acc[i][j] = fmaf(ar[i], br[j], acc[i][j]);
        }
        __syncthreads();
    }

    if (is_enc) {
        // rows = u, cols = e; bias varies along ROWS. Coalesced float4 stores.
        const int u0 = dir_col0;
        const int b  = scat_row0 >> 8;
        const int e0 = scat_row0 & 255;
        float4 bi = *(const float4*)&bias_enc[u0 + (ty << 2)];
        float bir[4] = {bi.x, bi.y, bi.z, bi.w};
#pragma unroll
        for (int i = 0; i < 4; ++i) {
            int u = u0 + (ty << 2) + i;
            float4 o = make_float4(acc[i][0] + bir[i], acc[i][1] + bir[i],
                                   acc[i][2] + bir[i], acc[i][3] + bir[i]);
            *(float4*)&d_encT[((size_t)((b << 9) + u)) * 256 + e0 + (tx << 2)] = o;
        }
    } else {
        const int c0 = dir_col0;
        float4 bi = *(const float4*)&bias_dec[c0 + (tx << 2)];
#pragma unroll
        for (int i = 0; i < 4; ++i) {
            int r = scat_row0 + (ty << 2) + i;
            float4 o = make_float4(acc[i][0] + bi.x, acc[i][1] + bi.y,
                                   acc[i][2] + bi.z, acc[i][3] + bi.w);
            *(float4*)&d_dec[(size_t)r * 512 + c0 + (tx << 2)] = o;
        }
    }
}

// ---------------------------------------------------------------------------
// Kernel 2: fused scores + softmax + context.
// Grid: 256 blocks = (b in 8) x (q-tile of 4 in 32). 1024 threads = 16 waves:
// 4 e-strips (64 e) x 4 u-quarters (128 u)  -> 16 waves/CU occupancy.
// score identity: sum_u w_u tanh(x) = const - 2*sum_u w_u/(1+e^{2x});
// const shifts (incl. bias_score) cancel in softmax.
// ---------------------------------------------------------------------------
__global__ __launch_bounds__(1024) void attend_kernel(
    const float* __restrict__ enc,     // [B, 256, 512]
    const float* __restrict__ d_encT,  // [B, 512, 256]
    const float* __restrict__ d_dec,   // [B, 128, 512]
    const float* __restrict__ Wscore,  // [512]
    float* __restrict__ out)           // [B, 128, 512]
{
    __shared__ float ddc[UN * 4];        // [u][q], pre-scaled by 2*log2(e)
    __shared__ float wsc[UN];
    __shared__ float accs[4][4][256];    // [u-quarter][q][e]
    __shared__ float wT[256][4];         // softmax weights [e][q]

    const float C = 2.8853900817779268f;       // 2*log2(e)
    const float LOG2E = 1.4426950408889634f;

    const int bid = blockIdx.x;
    const int b = bid >> 5, q0 = (bid & 31) << 2;
    const int tid = threadIdx.x;

    // stage dd * C into [u][q] layout (1024 threads, float2 each)
    {
        int q  = tid >> 8;            // 0..3
        int u2 = (tid & 255) << 1;    // 0..510
        float2 v = *(const float2*)&d_dec[((size_t)(b * S_DEC) + q0 + q) * UN + u2];
        ddc[(u2 + 0) * 4 + q] = v.x * C;
        ddc[(u2 + 1) * 4 + q] = v.y * C;
    }
    if (tid < 128) {
        *(float4*)&wsc[tid << 2] = *(const float4*)&Wscore[tid << 2];
    }
    __syncthreads();

    const int wv = tid >> 6, lane = tid & 63;
    const int e  = ((wv & 3) << 6) + lane;
    const int uq = wv >> 2, u0 = uq << 7;

    float a0 = 0.f, a1 = 0.f, a2 = 0.f, a3 = 0.f;
    const float* dptr = d_encT + ((size_t)b << 17) + e;   // + u*256 per step
#pragma unroll 4
    for (int u = u0; u < u0 + 128; ++u) {
        float de = dptr[u << 8];
        float4 dq = *(float4*)&ddc[u << 2];   // wave-uniform broadcast
        float w  = wsc[u];
        float t  = de * C;
        float s0 = t + dq.x, s1 = t + dq.y, s2 = t + dq.z, s3 = t + dq.w;
        float r0 = __builtin_amdgcn_rcpf(1.0f + __builtin_amdgcn_exp2f(s0));
        float r1 = __builtin_amdgcn_rcpf(1.0f + __builtin_amdgcn_exp2f(s1));
        float r2 = __builtin_amdgcn_rcpf(1.0f + __builtin_amdgcn_exp2f(s2));
        float r3 = __builtin_amdgcn_rcpf(1.0f + __builtin_amdgcn_exp2f(s3));
        a0 = fmaf(w, r0, a0);
        a1 = fmaf(w, r1, a1);
        a2 = fmaf(w, r2, a2);
        a3 = fmaf(w, r3, a3);
    }
    accs[uq][0][e] = a0;
    accs[uq][1][e] = a1;
    accs[uq][2][e] = a2;
    accs[uq][3][e] = a3;
    __syncthreads();

    // softmax over e (256) per q; logits = -2 * sum of quarter-accs
    if (wv < 4) {
        const int q = wv;
        float l[4];
        float m = -1e30f;
#pragma unroll
        for (int i = 0; i < 4; ++i) {
            int ee = lane + (i << 6);
            float a = accs[0][q][ee] + accs[1][q][ee] +
                      accs[2][q][ee] + accs[3][q][ee];
            l[i] = -2.f * a;
            m = fmaxf(m, l[i]);
        }
#pragma unroll
        for (int mk = 32; mk >= 1; mk >>= 1) m = fmaxf(m, __shfl_xor(m, mk, 64));
        float p[4];
        float s = 0.f;
#pragma unroll
        for (int i = 0; i < 4; ++i) {
            p[i] = __builtin_amdgcn_exp2f((l[i] - m) * LOG2E);
            s += p[i];
        }
#pragma unroll
        for (int mk = 32; mk >= 1; mk >>= 1) s += __shfl_xor(s, mk, 64);
        float inv = __builtin_amdgcn_rcpf(s);
#pragma unroll
        for (int i = 0; i < 4; ++i) wT[lane + (i << 6)][q] = p[i] * inv;
    }
    __syncthreads();

    // context: out[b, q0+q, d] = sum_e wT[e][q] * enc[b,e,d]
    // 1024 threads: q = tid>>8 (wave-uniform), d-pair = (tid&255)*2
    {
        const int q  = tid >> 8;
        const int d2 = (tid & 255) << 1;
        float c0_ = 0.f, c1_ = 0.f;
        const float* ep = enc + ((size_t)b * S_ENC) * DM + d2;
#pragma unroll 4
        for (int ee = 0; ee < 256; ++ee) {
            float2 x = *(const float2*)(ep + ((size_t)ee << 9));
            float w = wT[ee][q];        // wave-uniform broadcast
            c0_ = fmaf(w, x.x, c0_);
            c1_ = fmaf(w, x.y, c1_);
        }
        float* op = out + ((size_t)(b * S_DEC) + q0 + q) * DM + d2;
        *(float2*)op = make_float2(c0_, c1_);
    }
}

// ---------------------------------------------------------------------------
extern "C" void kernel_launch(void* const* d_in, const int* in_sizes, int n_in,
                              void* d_out, int out_size, void* d_ws, size_t ws_size,
                              hipStream_t stream) {
    const float* enc      = (const float*)d_in[0];  // [8,256,512]
    const float* dec      = (const float*)d_in[1];  // [8,128,512]
    const float* Wenc     = (const float*)d_in[2];  // [512,512]
    const float* Wdec     = (const float*)d_in[3];  // [512,512]
    const float* Wscore   = (const float*)d_in[4];  // [512,1]
    const float* bias_enc = (const float*)d_in[5];  // [512]
    const float* bias_dec = (const float*)d_in[6];  // [512]
    // d_in[7] = bias_score: constant shift, cancelled by softmax.
    float* out = (float*)d_out;

    float* ws = (float*)d_ws;
    float* d_encT = ws;                          // 8*512*256 floats = 4 MB
    float* d_decP = ws + (size_t)BB * 512 * 256; // 8*128*512 floats = 2 MB

    proj_kernel<<<384, 256, 0, stream>>>(enc, dec, Wenc, Wdec, bias_enc, bias_dec,
                                         d_encT, d_decP);
    attend_kernel<<<256, 1024, 0, stream>>>(enc, d_encT, d_decP, Wscore, out);
}

// Round 3
// 142.702 us; speedup vs baseline: 1.1184x; 1.1050x over previous
//
#include <hip/hip_runtime.h>

#define BB 8
#define S_ENC 256
#define S_DEC 128
#define DM 512
#define UN 512

typedef __attribute__((ext_vector_type(8))) __bf16 bf16x8;
typedef __attribute__((ext_vector_type(4))) float f32x4;

// pack two fp32 into two bf16 (truncation; residual captured by pack_lo)
__device__ inline unsigned int pack_hi(float x0, float x1) {
    return __builtin_amdgcn_perm(__float_as_uint(x1), __float_as_uint(x0), 0x07060302u);
}
__device__ inline unsigned int pack_lo(float x0, float x1) {
    float h0 = __uint_as_float(__float_as_uint(x0) & 0xFFFF0000u);
    float h1 = __uint_as_float(__float_as_uint(x1) & 0xFFFF0000u);
    return __builtin_amdgcn_perm(__float_as_uint(x1 - h1), __float_as_uint(x0 - h0), 0x07060302u);
}

// ---------------------------------------------------------------------------
// Kernel 0: transpose + bf16-split W:  WT_hi/lo[u][d] <- W[d][u]
// 128 blocks (2 matrices x 64 tiles of 64x64), 256 threads.
// ---------------------------------------------------------------------------
__global__ __launch_bounds__(256) void prep_w(
    const float* __restrict__ Wenc, const float* __restrict__ Wdec,
    unsigned short* __restrict__ Weh, unsigned short* __restrict__ Wel,
    unsigned short* __restrict__ Wdh, unsigned short* __restrict__ Wdl)
{
    __shared__ float L[64][68];
    const int bid = blockIdx.x;
    const float* W = (bid < 64) ? Wenc : Wdec;
    unsigned short* Th = (bid < 64) ? Weh : Wdh;
    unsigned short* Tl = (bid < 64) ? Wel : Wdl;
    const int tb = bid & 63;
    const int d0 = (tb >> 3) << 6, u0v = (tb & 7) << 6;
    const int t = threadIdx.x;
    {
        const int c4 = (t & 15) << 2;
#pragma unroll
        for (int i = 0; i < 4; ++i) {
            int row = (i << 4) + (t >> 4);
            *(float4*)&L[row][c4] = *(const float4*)&W[(size_t)(d0 + row) * 512 + u0v + c4];
        }
    }
    __syncthreads();
    const int u = t >> 2, dg = t & 3;
    unsigned int hw[8], lw[8];
#pragma unroll
    for (int j = 0; j < 8; ++j) {
        float x0 = L[(dg << 4) + (j << 1) + 0][u];
        float x1 = L[(dg << 4) + (j << 1) + 1][u];
        hw[j] = pack_hi(x0, x1);
        lw[j] = pack_lo(x0, x1);
    }
    size_t ob = (size_t)(u0v + u) * 512 + d0 + (dg << 4);
    *(uint4*)&Th[ob]     = make_uint4(hw[0], hw[1], hw[2], hw[3]);
    *(uint4*)&Th[ob + 8] = make_uint4(hw[4], hw[5], hw[6], hw[7]);
    *(uint4*)&Tl[ob]     = make_uint4(lw[0], lw[1], lw[2], lw[3]);
    *(uint4*)&Tl[ob + 8] = make_uint4(lw[4], lw[5], lw[6], lw[7]);
}

// ---------------------------------------------------------------------------
// Kernel 1: projections via split-bf16 MFMA (3 passes: AhBh + AhBl + AlBh).
// 64x64 tile, 256 thr = 2x2 waves of 32x32, BK=32, 16x16x32 bf16 MFMA.
//   enc blocks (bid<256):  A = WencT rows u (bf16 copy), B = enc rows e (cvt)
//       -> C[u][e], stored u-packed-by-4: d_encT4[b][u>>2][e][u&3] (float4!)
//   dec blocks (bid>=256): A = dec rows (cvt), B = WdecT rows u -> d_dec[r][u]
// ---------------------------------------------------------------------------
__global__ __launch_bounds__(256) void proj_kernel(
    const float* __restrict__ enc, const float* __restrict__ dec,
    const unsigned short* __restrict__ Weh, const unsigned short* __restrict__ Wel,
    const unsigned short* __restrict__ Wdh, const unsigned short* __restrict__ Wdl,
    const float* __restrict__ bias_enc, const float* __restrict__ bias_dec,
    float* __restrict__ d_encT4,   // [B][128][256][4]
    float* __restrict__ d_dec)     // [1024][512]
{
    __shared__ unsigned short Ah[64][40], Al[64][40], Bh[64][40], Bl[64][40];

    const int bid = blockIdx.x;
    const bool is_enc = (bid < 256);
    const int t = threadIdx.x;
    const int r = t >> 2, qc = t & 3;        // staging: row 0..63, 8-wide k-chunk

    const float* conv_src; int conv_row0;
    const unsigned short *cp_hi, *cp_lo; int cp_row0;
    int u0, e0, b, r0 = 0;
    if (is_enc) {
        b = bid >> 5;
        int sub = bid & 31;
        u0 = (sub >> 2) << 6;
        e0 = (sub & 3) << 6;
        conv_src = enc; conv_row0 = (b << 8) + e0;
        cp_hi = Weh; cp_lo = Wel; cp_row0 = u0;
    } else {
        int sub = bid - 256;
        r0 = (sub >> 3) << 6;
        u0 = (sub & 7) << 6;
        conv_src = dec; conv_row0 = r0;
        cp_hi = Wdh; cp_lo = Wdl; cp_row0 = u0;
        e0 = 0; b = 0;
    }

    unsigned short (*CvH)[40] = is_enc ? Bh : Ah;   // converted fp32 operand
    unsigned short (*CvL)[40] = is_enc ? Bl : Al;
    unsigned short (*CpH)[40] = is_enc ? Ah : Bh;   // pre-split W operand
    unsigned short (*CpL)[40] = is_enc ? Al : Bl;

    const float* cv_p          = &conv_src[(size_t)(conv_row0 + r) * 512 + (qc << 3)];
    const unsigned short* ch_p = &cp_hi[(size_t)(cp_row0 + r) * 512 + (qc << 3)];
    const unsigned short* cl_p = &cp_lo[(size_t)(cp_row0 + r) * 512 + (qc << 3)];

    const int lane = t & 63, wv = t >> 6;
    const int wy = wv >> 1, wx = wv & 1;
    const int frow = lane & 15, quad = lane >> 4;

    f32x4 acc[2][2] = {{{0.f,0.f,0.f,0.f},{0.f,0.f,0.f,0.f}},
                       {{0.f,0.f,0.f,0.f},{0.f,0.f,0.f,0.f}}};

    for (int k0 = 0; k0 < 512; k0 += 32) {
        float4 x0 = *(const float4*)(cv_p + k0);
        float4 x1 = *(const float4*)(cv_p + k0 + 4);
        uint4 wh = *(const uint4*)(ch_p + k0);
        uint4 wl = *(const uint4*)(cl_p + k0);
        unsigned int h0 = pack_hi(x0.x, x0.y), l0 = pack_lo(x0.x, x0.y);
        unsigned int h1 = pack_hi(x0.z, x0.w), l1 = pack_lo(x0.z, x0.w);
        unsigned int h2 = pack_hi(x1.x, x1.y), l2 = pack_lo(x1.x, x1.y);
        unsigned int h3 = pack_hi(x1.z, x1.w), l3 = pack_lo(x1.z, x1.w);
        __syncthreads();                      // prior iteration's reads done
        *(uint4*)&CvH[r][qc << 3] = make_uint4(h0, h1, h2, h3);
        *(uint4*)&CvL[r][qc << 3] = make_uint4(l0, l1, l2, l3);
        *(uint4*)&CpH[r][qc << 3] = wh;
        *(uint4*)&CpL[r][qc << 3] = wl;
        __syncthreads();
        bf16x8 ah[2], al[2], bh[2], bl[2];
#pragma unroll
        for (int f = 0; f < 2; ++f) {
            ah[f] = *(const bf16x8*)&Ah[(wy << 5) + (f << 4) + frow][quad << 3];
            al[f] = *(const bf16x8*)&Al[(wy << 5) + (f << 4) + frow][quad << 3];
            bh[f] = *(const bf16x8*)&Bh[(wx << 5) + (f << 4) + frow][quad << 3];
            bl[f] = *(const bf16x8*)&Bl[(wx << 5) + (f << 4) + frow][quad << 3];
        }
#pragma unroll
        for (int fm = 0; fm < 2; ++fm)
#pragma unroll
            for (int fn = 0; fn < 2; ++fn) {
                acc[fm][fn] = __builtin_amdgcn_mfma_f32_16x16x32_bf16(ah[fm], bh[fn], acc[fm][fn], 0, 0, 0);
                acc[fm][fn] = __builtin_amdgcn_mfma_f32_16x16x32_bf16(ah[fm], bl[fn], acc[fm][fn], 0, 0, 0);
                acc[fm][fn] = __builtin_amdgcn_mfma_f32_16x16x32_bf16(al[fm], bh[fn], acc[fm][fn], 0, 0, 0);
            }
    }

    // epilogue: C/D layout col = lane&15, row = quad*4 + reg
    if (is_enc) {
#pragma unroll
        for (int fm = 0; fm < 2; ++fm)
#pragma unroll
            for (int fn = 0; fn < 2; ++fn) {
                int u_base = u0 + (wy << 5) + (fm << 4) + (quad << 2);  // +reg = u
                int e      = e0 + (wx << 5) + (fn << 4) + frow;
                float4 bi = *(const float4*)&bias_enc[u_base];
                float4 o = make_float4(acc[fm][fn][0] + bi.x, acc[fm][fn][1] + bi.y,
                                       acc[fm][fn][2] + bi.z, acc[fm][fn][3] + bi.w);
                size_t idx = ((size_t)((b << 7) + (u_base >> 2)) << 10) + ((size_t)e << 2);
                *(float4*)&d_encT4[idx] = o;
            }
    } else {
#pragma unroll
        for (int fm = 0; fm < 2; ++fm)
#pragma unroll
            for (int fn = 0; fn < 2; ++fn) {
                int row_b = r0 + (wy << 5) + (fm << 4) + (quad << 2);
                int u_col = u0 + (wx << 5) + (fn << 4) + frow;
                float bi = bias_dec[u_col];
#pragma unroll
                for (int g = 0; g < 4; ++g)
                    d_dec[(size_t)(row_b + g) * 512 + u_col] = acc[fm][fn][g] + bi;
            }
    }
}

// ---------------------------------------------------------------------------
// Kernel 2: fused scores + softmax + context.
// 256 blocks = (b) x (q-tile of 4). 1024 thr = 16 waves: 4 e-strips x 4 u-qtrs.
// score loop reads de as float4 (4 u per load, u-packed layout) w/ prefetch.
// sum_u w_u tanh(x) = const - 2*sum w_u/(1+2^(x*2log2e)); consts cancel in softmax.
// ---------------------------------------------------------------------------
__device__ inline void score4(float dej, const float* ddq, float w,
                              float& a0, float& a1, float& a2, float& a3) {
    const float C = 2.8853900817779268f;   // 2*log2(e)
    float tt = dej * C;
    float4 dq = *(const float4*)ddq;
    float r0 = __builtin_amdgcn_rcpf(1.0f + __builtin_amdgcn_exp2f(tt + dq.x));
    float r1 = __builtin_amdgcn_rcpf(1.0f + __builtin_amdgcn_exp2f(tt + dq.y));
    float r2 = __builtin_amdgcn_rcpf(1.0f + __builtin_amdgcn_exp2f(tt + dq.z));
    float r3 = __builtin_amdgcn_rcpf(1.0f + __builtin_amdgcn_exp2f(tt + dq.w));
    a0 = fmaf(w, r0, a0);
    a1 = fmaf(w, r1, a1);
    a2 = fmaf(w, r2, a2);
    a3 = fmaf(w, r3, a3);
}

__global__ __launch_bounds__(1024) void attend_kernel(
    const float* __restrict__ enc,      // [B, 256, 512]
    const float* __restrict__ d_encT4,  // [B][128][256][4]
    const float* __restrict__ d_dec,    // [B*128, 512]
    const float* __restrict__ Wscore,   // [512]
    float* __restrict__ out)            // [B, 128, 512]
{
    __shared__ float ddc[UN * 4];        // [u][q], pre-scaled by 2*log2(e)
    __shared__ float wsc[UN];
    __shared__ float accs[4][4][256];    // [u-quarter][q][e]
    __shared__ float wT[256][4];         // softmax weights [e][q]

    const float C = 2.8853900817779268f;
    const float LOG2E = 1.4426950408889634f;

    const int bid = blockIdx.x;
    const int b = bid >> 5, q0 = (bid & 31) << 2;
    const int tid = threadIdx.x;

    {
        int q  = tid >> 8;
        int u2 = (tid & 255) << 1;
        float2 v = *(const float2*)&d_dec[((size_t)(b * S_DEC) + q0 + q) * UN + u2];
        ddc[(u2 + 0) * 4 + q] = v.x * C;
        ddc[(u2 + 1) * 4 + q] = v.y * C;
    }
    if (tid < 128) {
        *(float4*)&wsc[tid << 2] = *(const float4*)&Wscore[tid << 2];
    }
    __syncthreads();

    const int wv = tid >> 6, lane = tid & 63;
    const int e  = ((wv & 3) << 6) + lane;
    const int uq = wv >> 2, u0 = uq << 7;     // 128 u per wave = 32 groups of 4

    float a0 = 0.f, a1 = 0.f, a2 = 0.f, a3 = 0.f;
    const float4* dptr = (const float4*)d_encT4 +
                         (((size_t)(b << 7) + (u0 >> 2)) << 8) + e;
    float4 de = dptr[0];
#pragma unroll 2
    for (int g = 0; g < 32; ++g) {
        int gn = (g < 31) ? (g + 1) : 31;
        float4 de_n = dptr[(size_t)gn << 8];       // prefetch next group
        int u = u0 + (g << 2);
        score4(de.x, &ddc[(u + 0) << 2], wsc[u + 0], a0, a1, a2, a3);
        score4(de.y, &ddc[(u + 1) << 2], wsc[u + 1], a0, a1, a2, a3);
        score4(de.z, &ddc[(u + 2) << 2], wsc[u + 2], a0, a1, a2, a3);
        score4(de.w, &ddc[(u + 3) << 2], wsc[u + 3], a0, a1, a2, a3);
        de = de_n;
    }
    accs[uq][0][e] = a0;
    accs[uq][1][e] = a1;
    accs[uq][2][e] = a2;
    accs[uq][3][e] = a3;
    __syncthreads();

    if (wv < 4) {
        const int q = wv;
        float l[4];
        float m = -1e30f;
#pragma unroll
        for (int i = 0; i < 4; ++i) {
            int ee = lane + (i << 6);
            float a = accs[0][q][ee] + accs[1][q][ee] +
                      accs[2][q][ee] + accs[3][q][ee];
            l[i] = -2.f * a;
            m = fmaxf(m, l[i]);
        }
#pragma unroll
        for (int mk = 32; mk >= 1; mk >>= 1) m = fmaxf(m, __shfl_xor(m, mk, 64));
        float p[4];
        float s = 0.f;
#pragma unroll
        for (int i = 0; i < 4; ++i) {
            p[i] = __builtin_amdgcn_exp2f((l[i] - m) * LOG2E);
            s += p[i];
        }
#pragma unroll
        for (int mk = 32; mk >= 1; mk >>= 1) s += __shfl_xor(s, mk, 64);
        float inv = __builtin_amdgcn_rcpf(s);
#pragma unroll
        for (int i = 0; i < 4; ++i) wT[lane + (i << 6)][q] = p[i] * inv;
    }
    __syncthreads();

    {
        const int q  = tid >> 8;
        const int d2 = (tid & 255) << 1;
        float c0_ = 0.f, c1_ = 0.f;
        const float* ep = enc + ((size_t)b * S_ENC) * DM + d2;
#pragma unroll 4
        for (int ee = 0; ee < 256; ++ee) {
            float2 x = *(const float2*)(ep + ((size_t)ee << 9));
            float w = wT[ee][q];
            c0_ = fmaf(w, x.x, c0_);
            c1_ = fmaf(w, x.y, c1_);
        }
        float* op = out + ((size_t)(b * S_DEC) + q0 + q) * DM + d2;
        *(float2*)op = make_float2(c0_, c1_);
    }
}

// ---------------------------------------------------------------------------
extern "C" void kernel_launch(void* const* d_in, const int* in_sizes, int n_in,
                              void* d_out, int out_size, void* d_ws, size_t ws_size,
                              hipStream_t stream) {
    const float* enc      = (const float*)d_in[0];
    const float* dec      = (const float*)d_in[1];
    const float* Wenc     = (const float*)d_in[2];
    const float* Wdec     = (const float*)d_in[3];
    const float* Wscore   = (const float*)d_in[4];
    const float* bias_enc = (const float*)d_in[5];
    const float* bias_dec = (const float*)d_in[6];
    // d_in[7] = bias_score: constant shift, cancelled by softmax.
    float* out = (float*)d_out;

    float* ws = (float*)d_ws;
    float* d_encT4 = ws;                               // 1,048,576 floats (4 MB)
    float* d_decP  = ws + 1048576;                     // 524,288 floats (2 MB)
    unsigned short* Weh = (unsigned short*)(ws + 1048576 + 524288);
    unsigned short* Wel = Weh + 262144;                // 4 x 512 KB = 2 MB
    unsigned short* Wdh = Wel + 262144;
    unsigned short* Wdl = Wdh + 262144;                // total ws use: 8 MB

    prep_w<<<128, 256, 0, stream>>>(Wenc, Wdec, Weh, Wel, Wdh, Wdl);
    proj_kernel<<<384, 256, 0, stream>>>(enc, dec, Weh, Wel, Wdh, Wdl,
                                         bias_enc, bias_dec, d_encT4, d_decP);
    attend_kernel<<<256, 1024, 0, stream>>>(enc, d_encT4, d_decP, Wscore, out);
}

// Round 4
// 141.979 us; speedup vs baseline: 1.1241x; 1.0051x over previous
//
#include <hip/hip_runtime.h>

#define BB 8
#define S_ENC 256
#define S_DEC 128
#define DM 512
#define UN 512

typedef __attribute__((ext_vector_type(8))) __bf16 bf16x8;
typedef __attribute__((ext_vector_type(4))) float f32x4;

// pack two fp32 into two bf16 (truncation; residual captured by pack_lo)
__device__ inline unsigned int pack_hi(float x0, float x1) {
    return __builtin_amdgcn_perm(__float_as_uint(x1), __float_as_uint(x0), 0x07060302u);
}
__device__ inline unsigned int pack_lo(float x0, float x1) {
    float h0 = __uint_as_float(__float_as_uint(x0) & 0xFFFF0000u);
    float h1 = __uint_as_float(__float_as_uint(x1) & 0xFFFF0000u);
    return __builtin_amdgcn_perm(__float_as_uint(x1 - h1), __float_as_uint(x0 - h0), 0x07060302u);
}

// ---------------------------------------------------------------------------
// Kernel 0: transpose + bf16-split W:  WT_hi/lo[u][d] <- W[d][u]
// ---------------------------------------------------------------------------
__global__ __launch_bounds__(256) void prep_w(
    const float* __restrict__ Wenc, const float* __restrict__ Wdec,
    unsigned short* __restrict__ Weh, unsigned short* __restrict__ Wel,
    unsigned short* __restrict__ Wdh, unsigned short* __restrict__ Wdl)
{
    __shared__ float L[64][68];
    const int bid = blockIdx.x;
    const float* W = (bid < 64) ? Wenc : Wdec;
    unsigned short* Th = (bid < 64) ? Weh : Wdh;
    unsigned short* Tl = (bid < 64) ? Wel : Wdl;
    const int tb = bid & 63;
    const int d0 = (tb >> 3) << 6, u0v = (tb & 7) << 6;
    const int t = threadIdx.x;
    {
        const int c4 = (t & 15) << 2;
#pragma unroll
        for (int i = 0; i < 4; ++i) {
            int row = (i << 4) + (t >> 4);
            *(float4*)&L[row][c4] = *(const float4*)&W[(size_t)(d0 + row) * 512 + u0v + c4];
        }
    }
    __syncthreads();
    const int u = t >> 2, dg = t & 3;
    unsigned int hw[8], lw[8];
#pragma unroll
    for (int j = 0; j < 8; ++j) {
        float x0 = L[(dg << 4) + (j << 1) + 0][u];
        float x1 = L[(dg << 4) + (j << 1) + 1][u];
        hw[j] = pack_hi(x0, x1);
        lw[j] = pack_lo(x0, x1);
    }
    size_t ob = (size_t)(u0v + u) * 512 + d0 + (dg << 4);
    *(uint4*)&Th[ob]     = make_uint4(hw[0], hw[1], hw[2], hw[3]);
    *(uint4*)&Th[ob + 8] = make_uint4(hw[4], hw[5], hw[6], hw[7]);
    *(uint4*)&Tl[ob]     = make_uint4(lw[0], lw[1], lw[2], lw[3]);
    *(uint4*)&Tl[ob + 8] = make_uint4(lw[4], lw[5], lw[6], lw[7]);
}

// ---------------------------------------------------------------------------
// Kernel 1: projections via split-bf16 MFMA (AhBh + AhBl + AlBh).
// 64x64 tile, 256 thr = 2x2 waves of 32x32, BK=32.
// LDS row stride 48 shorts (96 B) -> 16B-aligned ds_read_b128/ds_write_b128.
// Register prefetch of next K-tile overlaps global latency with MFMA.
//   enc blocks: C[u][e]*Cs stored u-packed-by-4: d_encT4[b][u>>2][e][u&3]
//   dec blocks: C[(b,q)][u] + bias -> d_dec row-major (raw, no scale)
// ---------------------------------------------------------------------------
__global__ __launch_bounds__(256) void proj_kernel(
    const float* __restrict__ enc, const float* __restrict__ dec,
    const unsigned short* __restrict__ Weh, const unsigned short* __restrict__ Wel,
    const unsigned short* __restrict__ Wdh, const unsigned short* __restrict__ Wdl,
    const float* __restrict__ bias_enc, const float* __restrict__ bias_dec,
    float* __restrict__ d_encT4,   // [B][128][256][4], pre-scaled by 2*log2(e)
    float* __restrict__ d_dec)     // [1024][512]
{
    __shared__ unsigned short Ah[64][48], Al[64][48], Bh[64][48], Bl[64][48];

    const float Cs = 2.8853900817779268f;   // 2*log2(e)

    const int bid = blockIdx.x;
    const bool is_enc = (bid < 256);
    const int t = threadIdx.x;
    const int r = t >> 2, qc = t & 3;        // staging: row 0..63, 8-wide k-chunk

    const float* conv_src; int conv_row0;
    const unsigned short *cp_hi, *cp_lo; int cp_row0;
    int u0, e0, b, r0 = 0;
    if (is_enc) {
        b = bid >> 5;
        int sub = bid & 31;
        u0 = (sub >> 2) << 6;
        e0 = (sub & 3) << 6;
        conv_src = enc; conv_row0 = (b << 8) + e0;
        cp_hi = Weh; cp_lo = Wel; cp_row0 = u0;
    } else {
        int sub = bid - 256;
        r0 = (sub >> 3) << 6;
        u0 = (sub & 7) << 6;
        conv_src = dec; conv_row0 = r0;
        cp_hi = Wdh; cp_lo = Wdl; cp_row0 = u0;
        e0 = 0; b = 0;
    }

    unsigned short (*CvH)[48] = is_enc ? Bh : Ah;   // converted fp32 operand
    unsigned short (*CvL)[48] = is_enc ? Bl : Al;
    unsigned short (*CpH)[48] = is_enc ? Ah : Bh;   // pre-split W operand
    unsigned short (*CpL)[48] = is_enc ? Al : Bl;

    const float* cv_p          = &conv_src[(size_t)(conv_row0 + r) * 512 + (qc << 3)];
    const unsigned short* ch_p = &cp_hi[(size_t)(cp_row0 + r) * 512 + (qc << 3)];
    const unsigned short* cl_p = &cp_lo[(size_t)(cp_row0 + r) * 512 + (qc << 3)];

    const int lane = t & 63, wv = t >> 6;
    const int wy = wv >> 1, wx = wv & 1;
    const int frow = lane & 15, quad = lane >> 4;

    f32x4 acc[2][2] = {{{0.f,0.f,0.f,0.f},{0.f,0.f,0.f,0.f}},
                       {{0.f,0.f,0.f,0.f},{0.f,0.f,0.f,0.f}}};

    // prologue prefetch (k0 = 0)
    float4 nx0 = *(const float4*)cv_p;
    float4 nx1 = *(const float4*)(cv_p + 4);
    uint4  nwh = *(const uint4*)ch_p;
    uint4  nwl = *(const uint4*)cl_p;

    for (int k0 = 0; k0 < 512; k0 += 32) {
        float4 x0 = nx0, x1 = nx1;
        uint4 wh = nwh, wl = nwl;
        unsigned int h0 = pack_hi(x0.x, x0.y), l0 = pack_lo(x0.x, x0.y);
        unsigned int h1 = pack_hi(x0.z, x0.w), l1 = pack_lo(x0.z, x0.w);
        unsigned int h2 = pack_hi(x1.x, x1.y), l2 = pack_lo(x1.x, x1.y);
        unsigned int h3 = pack_hi(x1.z, x1.w), l3 = pack_lo(x1.z, x1.w);
        __syncthreads();                      // prior iteration's reads done
        *(uint4*)&CvH[r][qc << 3] = make_uint4(h0, h1, h2, h3);
        *(uint4*)&CvL[r][qc << 3] = make_uint4(l0, l1, l2, l3);
        *(uint4*)&CpH[r][qc << 3] = wh;
        *(uint4*)&CpL[r][qc << 3] = wl;
        __syncthreads();
        if (k0 + 32 < 512) {                  // prefetch next tile (in flight
            nx0 = *(const float4*)(cv_p + k0 + 32);        // during MFMA below)
            nx1 = *(const float4*)(cv_p + k0 + 36);
            nwh = *(const uint4*)(ch_p + k0 + 32);
            nwl = *(const uint4*)(cl_p + k0 + 32);
        }
        bf16x8 ah[2], al[2], bh[2], bl[2];
#pragma unroll
        for (int f = 0; f < 2; ++f) {
            ah[f] = *(const bf16x8*)&Ah[(wy << 5) + (f << 4) + frow][quad << 3];
            al[f] = *(const bf16x8*)&Al[(wy << 5) + (f << 4) + frow][quad << 3];
            bh[f] = *(const bf16x8*)&Bh[(wx << 5) + (f << 4) + frow][quad << 3];
            bl[f] = *(const bf16x8*)&Bl[(wx << 5) + (f << 4) + frow][quad << 3];
        }
#pragma unroll
        for (int fm = 0; fm < 2; ++fm)
#pragma unroll
            for (int fn = 0; fn < 2; ++fn) {
                acc[fm][fn] = __builtin_amdgcn_mfma_f32_16x16x32_bf16(ah[fm], bh[fn], acc[fm][fn], 0, 0, 0);
                acc[fm][fn] = __builtin_amdgcn_mfma_f32_16x16x32_bf16(ah[fm], bl[fn], acc[fm][fn], 0, 0, 0);
                acc[fm][fn] = __builtin_amdgcn_mfma_f32_16x16x32_bf16(al[fm], bh[fn], acc[fm][fn], 0, 0, 0);
            }
    }

    // epilogue: C/D layout col = lane&15, row = quad*4 + reg
    if (is_enc) {
#pragma unroll
        for (int fm = 0; fm < 2; ++fm)
#pragma unroll
            for (int fn = 0; fn < 2; ++fn) {
                int u_base = u0 + (wy << 5) + (fm << 4) + (quad << 2);  // +reg = u
                int e      = e0 + (wx << 5) + (fn << 4) + frow;
                float4 bi = *(const float4*)&bias_enc[u_base];
                // store (acc+bias)*Cs  (pre-scaled for the exp2 path)
                float4 o = make_float4((acc[fm][fn][0] + bi.x) * Cs,
                                       (acc[fm][fn][1] + bi.y) * Cs,
                                       (acc[fm][fn][2] + bi.z) * Cs,
                                       (acc[fm][fn][3] + bi.w) * Cs);
                size_t idx = ((size_t)((b << 7) + (u_base >> 2)) << 10) + ((size_t)e << 2);
                *(float4*)&d_encT4[idx] = o;
            }
    } else {
#pragma unroll
        for (int fm = 0; fm < 2; ++fm)
#pragma unroll
            for (int fn = 0; fn < 2; ++fn) {
                int row_b = r0 + (wy << 5) + (fm << 4) + (quad << 2);
                int u_col = u0 + (wx << 5) + (fn << 4) + frow;
                float bi = bias_dec[u_col];
#pragma unroll
                for (int g = 0; g < 4; ++g)
                    d_dec[(size_t)(row_b + g) * 512 + u_col] = acc[fm][fn][g] + bi;
            }
    }
}

// ---------------------------------------------------------------------------
// Kernel 2: fused scores + softmax + context. TRANS-FREE score loop.
// s(q,e) = const - 2*sum_u w_u/(1 + 2^(de'+dq')); 2^(de'+dq') = E_{e,u}*G_{q,u}
//   E = 2^de' via rndne + deg-5 Taylor(2^f) + exponent-bit add (pure VALU)
//   1/(1+E*G) via magic-seed + 2 Newton steps (pure VALU)
// G precomputed once per block into LDS (2048 exp2 total).
// ---------------------------------------------------------------------------
#define TA1 0.69314718056f
#define TA2 0.24022650700f
#define TA3 0.05550410866f
#define TA4 0.00961812911f
#define TA5 0.00133335581f

__device__ inline void score_u(float t, const float* Gp, float w,
                               float& a0, float& a1, float& a2, float& a3) {
    float n = rintf(t);
    float f = t - n;
    int  i  = (int)n;
    float p = fmaf(f, TA5, TA4);
    p = fmaf(f, p, TA3);
    p = fmaf(f, p, TA2);
    p = fmaf(f, p, TA1);
    p = fmaf(f, p, 1.0f);
    float E = __uint_as_float(__float_as_uint(p) + (((unsigned)i) << 23));
    float4 G = *(const float4*)Gp;   // wave-uniform broadcast
    float D0 = fmaf(E, G.x, 1.0f);
    float D1 = fmaf(E, G.y, 1.0f);
    float D2 = fmaf(E, G.z, 1.0f);
    float D3 = fmaf(E, G.w, 1.0f);
    float s0 = __uint_as_float(0x7EF311C3u - __float_as_uint(D0));
    float s1 = __uint_as_float(0x7EF311C3u - __float_as_uint(D1));
    float s2 = __uint_as_float(0x7EF311C3u - __float_as_uint(D2));
    float s3 = __uint_as_float(0x7EF311C3u - __float_as_uint(D3));
    s0 *= fmaf(-D0, s0, 2.0f);  s0 *= fmaf(-D0, s0, 2.0f);
    s1 *= fmaf(-D1, s1, 2.0f);  s1 *= fmaf(-D1, s1, 2.0f);
    s2 *= fmaf(-D2, s2, 2.0f);  s2 *= fmaf(-D2, s2, 2.0f);
    s3 *= fmaf(-D3, s3, 2.0f);  s3 *= fmaf(-D3, s3, 2.0f);
    a0 = fmaf(w, s0, a0);
    a1 = fmaf(w, s1, a1);
    a2 = fmaf(w, s2, a2);
    a3 = fmaf(w, s3, a3);
}

__global__ __launch_bounds__(1024) void attend_kernel(
    const float* __restrict__ enc,      // [B, 256, 512]
    const float* __restrict__ d_encT4,  // [B][128][256][4], pre-scaled
    const float* __restrict__ d_dec,    // [B*128, 512]
    const float* __restrict__ Wscore,   // [512]
    float* __restrict__ out)            // [B, 128, 512]
{
    __shared__ float Gq[UN][4];          // 2^(dd*C) per [u][q]
    __shared__ float wsc[UN];
    __shared__ float accs[4][4][256];    // [u-quarter][q][e]
    __shared__ float wT[256][4];         // softmax weights [e][q]

    const float C = 2.8853900817779268f;
    const float LOG2E = 1.4426950408889634f;

    const int bid = blockIdx.x;
    const int b = bid >> 5, q0 = (bid & 31) << 2;
    const int tid = threadIdx.x;

    {
        int q  = tid >> 8;
        int u2 = (tid & 255) << 1;
        float2 v = *(const float2*)&d_dec[((size_t)(b * S_DEC) + q0 + q) * UN + u2];
        Gq[u2 + 0][q] = __builtin_amdgcn_exp2f(v.x * C);
        Gq[u2 + 1][q] = __builtin_amdgcn_exp2f(v.y * C);
    }
    if (tid < 128) {
        *(float4*)&wsc[tid << 2] = *(const float4*)&Wscore[tid << 2];
    }
    __syncthreads();

    const int wv = tid >> 6, lane = tid & 63;
    const int e  = ((wv & 3) << 6) + lane;
    const int uq = wv >> 2, u0 = uq << 7;     // 128 u per wave = 32 groups of 4

    float a0 = 0.f, a1 = 0.f, a2 = 0.f, a3 = 0.f;
    const float4* dptr = (const float4*)d_encT4 +
                         (((size_t)(b << 7) + (u0 >> 2)) << 8) + e;
    float4 de = dptr[0];
    for (int g = 0; g < 32; ++g) {
        int gn = (g < 31) ? (g + 1) : 31;
        float4 de_n = dptr[(size_t)gn << 8];       // prefetch next group
        int u = u0 + (g << 2);
        float4 w4 = *(const float4*)&wsc[u];
        score_u(de.x, &Gq[u + 0][0], w4.x, a0, a1, a2, a3);
        score_u(de.y, &Gq[u + 1][0], w4.y, a0, a1, a2, a3);
        score_u(de.z, &Gq[u + 2][0], w4.z, a0, a1, a2, a3);
        score_u(de.w, &Gq[u + 3][0], w4.w, a0, a1, a2, a3);
        de = de_n;
    }
    accs[uq][0][e] = a0;
    accs[uq][1][e] = a1;
    accs[uq][2][e] = a2;
    accs[uq][3][e] = a3;
    __syncthreads();

    if (wv < 4) {
        const int q = wv;
        float l[4];
        float m = -1e30f;
#pragma unroll
        for (int i = 0; i < 4; ++i) {
            int ee = lane + (i << 6);
            float a = accs[0][q][ee] + accs[1][q][ee] +
                      accs[2][q][ee] + accs[3][q][ee];
            l[i] = -2.f * a;
            m = fmaxf(m, l[i]);
        }
#pragma unroll
        for (int mk = 32; mk >= 1; mk >>= 1) m = fmaxf(m, __shfl_xor(m, mk, 64));
        float p[4];
        float s = 0.f;
#pragma unroll
        for (int i = 0; i < 4; ++i) {
            p[i] = __builtin_amdgcn_exp2f((l[i] - m) * LOG2E);
            s += p[i];
        }
#pragma unroll
        for (int mk = 32; mk >= 1; mk >>= 1) s += __shfl_xor(s, mk, 64);
        float inv = __builtin_amdgcn_rcpf(s);
#pragma unroll
        for (int i = 0; i < 4; ++i) wT[lane + (i << 6)][q] = p[i] * inv;
    }
    __syncthreads();

    {
        const int q  = tid >> 8;
        const int d2 = (tid & 255) << 1;
        float c0_ = 0.f, c1_ = 0.f;
        const float* ep = enc + ((size_t)b * S_ENC) * DM + d2;
#pragma unroll 4
        for (int ee = 0; ee < 256; ++ee) {
            float2 x = *(const float2*)(ep + ((size_t)ee << 9));
            float w = wT[ee][q];
            c0_ = fmaf(w, x.x, c0_);
            c1_ = fmaf(w, x.y, c1_);
        }
        float* op = out + ((size_t)(b * S_DEC) + q0 + q) * DM + d2;
        *(float2*)op = make_float2(c0_, c1_);
    }
}

// ---------------------------------------------------------------------------
extern "C" void kernel_launch(void* const* d_in, const int* in_sizes, int n_in,
                              void* d_out, int out_size, void* d_ws, size_t ws_size,
                              hipStream_t stream) {
    const float* enc      = (const float*)d_in[0];
    const float* dec      = (const float*)d_in[1];
    const float* Wenc     = (const float*)d_in[2];
    const float* Wdec     = (const float*)d_in[3];
    const float* Wscore   = (const float*)d_in[4];
    const float* bias_enc = (const float*)d_in[5];
    const float* bias_dec = (const float*)d_in[6];
    // d_in[7] = bias_score: constant shift, cancelled by softmax.
    float* out = (float*)d_out;

    float* ws = (float*)d_ws;
    float* d_encT4 = ws;                               // 1,048,576 floats (4 MB)
    float* d_decP  = ws + 1048576;                     // 524,288 floats (2 MB)
    unsigned short* Weh = (unsigned short*)(ws + 1048576 + 524288);
    unsigned short* Wel = Weh + 262144;                // 4 x 512 KB = 2 MB
    unsigned short* Wdh = Wel + 262144;
    unsigned short* Wdl = Wdh + 262144;                // total ws use: 8 MB

    prep_w<<<128, 256, 0, stream>>>(Wenc, Wdec, Weh, Wel, Wdh, Wdl);
    proj_kernel<<<384, 256, 0, stream>>>(enc, dec, Weh, Wel, Wdh, Wdl,
                                         bias_enc, bias_dec, d_encT4, d_decP);
    attend_kernel<<<256, 1024, 0, stream>>>(enc, d_encT4, d_decP, Wscore, out);
}